// Round 4
// baseline (239.437 us; speedup 1.0000x reference)
//
#include <hip/hip_runtime.h>
#include <math.h>

// Problem constants
#define NPTS  2048
// ws float offsets (max 131072 floats = 512 KB)
#define OFF_M   0        // [64][61]  M[b][c*6+a], Sdw at [b][60]
#define OFF_T2  4096     // [64][18]  T2[m][a*3+j]
#define OFF_V   8192     // [384][128] V[ma][v]  (16B-aligned rows)
#define OFF_Z   57344    // [64][128]
#define OFF_GP  65536    // [512][128] per-block bn3 partials (S in 0..63, Q in 64..127)

// ---------------------------------------------------------------------------
// A = weight fold (blocks 0..196) U per-batch moments (blocks 197..260).
// All blocks independent; disjoint global writes. Bit-deterministic.
__global__ __launch_bounds__(256) void k_A(const float* __restrict__ x,
                                           const float* __restrict__ Wm0,
                                           const float* __restrict__ Wdc,
                                           float* __restrict__ ws) {
    __shared__ float red[61 * 257];
    int blk = blockIdx.x, t = threadIdx.x;
    if (blk < 197) {
        int idx = blk * 256 + t;
        if (idx < 384 * 128) {
            int ma = idx >> 7, v = idx & 127;
            int a = ma % 6;
            const float* wm = Wm0 + (ma / 6) * 256;   // wave-uniform
            float s = 0.f;
#pragma unroll 8
            for (int e = 0; e < 256; ++e)
                s = fmaf(wm[e], Wdc[(e * 6 + a) * 131 + 3 + v], s);
            ws[OFF_V + ma * 128 + v] = s;
        } else if (idx < 384 * 128 + 64 * 18) {
            int j2 = idx - 384 * 128;
            int m = j2 / 18, r = j2 % 18;
            int a = r / 3, j = r % 3;
            const float* wm = Wm0 + m * 256;
            float s = 0.f;
#pragma unroll 8
            for (int e = 0; e < 256; ++e)
                s = fmaf(wm[e], Wdc[(e * 6 + a) * 131 + j], s);
            ws[OFF_T2 + m * 18 + r] = s;
        }
        return;
    }
    // ---- per-batch moments ----
    int b = blk - 197;
    float acc[61];
#pragma unroll
    for (int i = 0; i < 61; ++i) acc[i] = 0.f;
    for (int k = 0; k < 8; ++k) {
        int n = t + 256 * k;
        const float* xp = x + (size_t)(b * NPTS + n) * 10;
        float xv[10];
#pragma unroll
        for (int j = 0; j < 5; ++j) {
            float2 v = *(const float2*)(xp + 2 * j);
            xv[2 * j] = v.x; xv[2 * j + 1] = v.y;
        }
        float x0 = xv[0], x1 = xv[1], x2 = xv[2];
        float rn = x0 * x0 + x1 * x1 + x2 * x2;
        float norm = sqrtf(rn);
        float inv = 1.f / (norm + 1e-8f);
        float c2[6];
        c2[0] = fmaxf(x2, 0.f) * inv; c2[1] = fmaxf(-x2, 0.f) * inv;
        c2[2] = fmaxf(x1, 0.f) * inv; c2[3] = fmaxf(-x1, 0.f) * inv;
        c2[4] = fmaxf(x0, 0.f) * inv; c2[5] = fmaxf(-x0, 0.f) * inv;
#pragma unroll
        for (int a = 0; a < 6; ++a) c2[a] *= c2[a];
        float dw = 1.f - (rn - 1.f) * (1.f / 3.f);
        if (dw < 0.f) dw = 0.f;
        if (norm <= 0.f) dw = 0.f;
        float cw[6];
#pragma unroll
        for (int a = 0; a < 6; ++a) cw[a] = c2[a] * dw;
#pragma unroll
        for (int c = 0; c < 10; ++c) {
            float dv = (c < 7) ? xv[3 + c] : xv[c - 7];
#pragma unroll
            for (int a = 0; a < 6; ++a)
                acc[c * 6 + a] = fmaf(dv, cw[a], acc[c * 6 + a]);
        }
        acc[60] += dw;
    }
#pragma unroll
    for (int i = 0; i < 61; ++i) red[i * 257 + t] = acc[i];
    __syncthreads();
    if (t < 61) {
        float s = 0.f;
#pragma unroll 8
        for (int j = 0; j < 256; ++j) s += red[t * 257 + j];
        ws[OFF_M + b * 61 + t] = s;
    }
}

// ---------------------------------------------------------------------------
// B: h1 + BN1 + d2 + BN2 + enc + z, all inside one block with LDS only.
// 16 blocks (vb=blk>>2 picks 32 z-columns, bb=blk&3 picks 16 batch rows).
// Each block redundantly computes h1/BN1/d2-stats from M (deterministic,
// identical across blocks); enc never touches global memory -> no races.
__global__ __launch_bounds__(256) void k_B(const float* __restrict__ Wdir,
                                           const float* __restrict__ g1,
                                           const float* __restrict__ b1,
                                           const float* __restrict__ Wdir2,
                                           const float* __restrict__ g2,
                                           const float* __restrict__ b2,
                                           const float* __restrict__ Wf1,
                                           const float* __restrict__ bf1,
                                           float* __restrict__ ws) {
    __shared__ float regA[4112];   // phase 0-1: Ml[64*61]; phase 3-4: El[16][257]
    __shared__ float regB[4160];   // phase 1-3: h1[64][65]; phase 4: Wl[32][129]
    __shared__ float sc[64], of[64];
    int t = threadIdx.x;
    int bb = blockIdx.x & 3, vb = blockIdx.x >> 2;
    for (int g = t; g < 3904; g += 256) regA[g] = ws[OFF_M + g];   // coalesced
    __syncthreads();
    // phase 1: h1[b][m], thread owns m for 16 b's; Wdir row in registers
    int m = t & 63, bg = t >> 6;
    {
        float Wr[60];
        const float* wsrc = Wdir + m * 60;
#pragma unroll
        for (int r = 0; r < 60; ++r) Wr[r] = wsrc[r];
#pragma unroll
        for (int i = 0; i < 16; ++i) {
            int b = bg * 16 + i;
            const float* Mb = regA + b * 61;        // broadcast LDS reads
            float s = 0.f;
#pragma unroll
            for (int a = 0; a < 6; ++a)
#pragma unroll
                for (int c = 0; c < 10; ++c)
                    s = fmaf(Wr[a * 10 + c], Mb[c * 6 + a], s);
            regB[b * 65 + m] = s / Mb[60];
        }
    }
    __syncthreads();
    // phase 2: BN1 stats + apply
    if (t < 64) {
        float s = 0.f, q = 0.f;
#pragma unroll 8
        for (int b = 0; b < 64; ++b) { float v = regB[b * 65 + t]; s += v; q = fmaf(v, v, q); }
        float mean = s * (1.f / 64.f);
        float var = q * (1.f / 64.f) - mean * mean;
        float scale = g1[t] * rsqrtf(var + 1e-5f);
        sc[t] = scale; of[t] = b1[t] - mean * scale;
    }
    __syncthreads();
#pragma unroll
    for (int i = 0; i < 16; ++i) {
        int b = bg * 16 + i;
        float v = regB[b * 65 + m];
        regB[b * 65 + m] = fmaxf(fmaf(v, sc[m], of[m]), 0.f);
    }
    __syncthreads();
    // phase 3: thread owns e=t; d2[b][e] over all b (stats exact); rows of
    // this block's bb-tile land in El; per-thread BN2 scale applied in place.
    {
        float w2[64];
        const float* wp = Wdir2 + t * 64;
#pragma unroll
        for (int r = 0; r < 64; ++r) w2[r] = wp[r];
        float s = 0.f, q = 0.f;
        for (int b = 0; b < 64; ++b) {
            const float* h = regB + b * 65;         // broadcast LDS reads
            float acc = 0.f;
#pragma unroll
            for (int r = 0; r < 64; ++r) acc = fmaf(h[r], w2[r], acc);
            s += acc; q = fmaf(acc, acc, q);
            if ((b >> 4) == bb) regA[(b & 15) * 257 + t] = acc;   // raw d2
        }
        float mean = s * (1.f / 64.f);
        float var = q * (1.f / 64.f) - mean * mean;
        float scale = g2[t] * rsqrtf(var + 1e-5f);
        float off = b2[t] - mean * scale;
#pragma unroll
        for (int i = 0; i < 16; ++i) {
            float vv = regA[i * 257 + t];
            regA[i * 257 + t] = fmaxf(fmaf(vv, scale, off), 0.f);  // enc
        }
    }
    __syncthreads();
    // phase 4: z tile; Wf1 half-staged into regB (h1 dead)
    int v_loc = t & 31, b_loc = t >> 5;
    float s0 = 0.f, s1 = 0.f;
    for (int half = 0; half < 2; ++half) {
        for (int g = t; g < 4096; g += 256)
            regB[(g >> 7) * 129 + (g & 127)] =
                Wf1[(vb * 32 + (g >> 7)) * 256 + half * 128 + (g & 127)];
        __syncthreads();
        const float* W  = regB + v_loc * 129;
        const float* E0 = regA + b_loc * 257 + half * 128;
        const float* E1 = regA + (b_loc + 8) * 257 + half * 128;
#pragma unroll 8
        for (int e = 0; e < 128; ++e) {
            float w = W[e];
            s0 = fmaf(E0[e], w, s0);
            s1 = fmaf(E1[e], w, s1);
        }
        __syncthreads();
    }
    int v = vb * 32 + v_loc;
    float bias = bf1[v];
    ws[OFF_Z + (bb * 16 + b_loc) * 128 + v] = s0 + bias;
    ws[OFF_Z + (bb * 16 + b_loc + 8) * 128 + v] = s1 + bias;
}

// ---------------------------------------------------------------------------
// C: per-block redundant U2/C2 (from Z,V,Wcm - all prior-kernel data) + BN3
// stats over this block's 256 points -> non-atomic GP partial write.
__global__ __launch_bounds__(256) void k_C(const float* __restrict__ x,
                                           const float* __restrict__ Wcm,
                                           const float* __restrict__ bcm,
                                           float* __restrict__ ws) {
    __shared__ float zl[128];
    __shared__ float U2l[384];
    __shared__ float C2l[64];
    __shared__ float r2[512];
    __shared__ float T2l[1152];
    int blk = blockIdx.x, t = threadIdx.x;
    int b = blk >> 3, c = blk & 7;
    if (t < 128) zl[t] = ws[OFF_Z + b * 128 + t];
    for (int g = t; g < 1152; g += 256) T2l[g] = ws[OFF_T2 + g];
    __syncthreads();
    {
        const float4* Vp = (const float4*)(ws + OFF_V + t * 128);
        float s = 0.f;
#pragma unroll
        for (int i = 0; i < 32; ++i) {
            float4 v = Vp[i];
            s = fmaf(zl[4 * i], v.x, s);     s = fmaf(zl[4 * i + 1], v.y, s);
            s = fmaf(zl[4 * i + 2], v.z, s); s = fmaf(zl[4 * i + 3], v.w, s);
        }
        U2l[t] = s;
    }
    if (t < 128) {
        const float4* Vp = (const float4*)(ws + OFF_V + (256 + t) * 128);
        float s = 0.f;
#pragma unroll
        for (int i = 0; i < 32; ++i) {
            float4 v = Vp[i];
            s = fmaf(zl[4 * i], v.x, s);     s = fmaf(zl[4 * i + 1], v.y, s);
            s = fmaf(zl[4 * i + 2], v.z, s); s = fmaf(zl[4 * i + 3], v.w, s);
        }
        U2l[256 + t] = s;
    }
    if (c == 0 && t < 64) {
        const float* w = Wcm + t * 131;
        float s = bcm[t];
#pragma unroll 8
        for (int i = 0; i < 128; ++i) s = fmaf(zl[i], w[i], s);
        const float* xp = x + (size_t)b * NPTS * 10;
        s = fmaf(xp[0], w[128], s);
        s = fmaf(xp[1], w[129], s);
        s = fmaf(xp[2], w[130], s);
        C2l[t] = s;
    }
    __syncthreads();
    int m = t & 63, wid = t >> 6;
    float T[18], U[6];
#pragma unroll
    for (int r = 0; r < 18; ++r) T[r] = T2l[m * 18 + r];
#pragma unroll
    for (int a = 0; a < 6; ++a) U[a] = U2l[m * 6 + a];
    bool has0 = (c == 0) && (wid == 0);
    float c2v = has0 ? C2l[m] : 0.f;
    float accS = 0.f, accQ = 0.f;
    int p0 = c * 256 + wid * 64;
    const float* xb = x + (size_t)b * NPTS * 10;
#pragma unroll 4
    for (int i = 0; i < 64; ++i) {
        const float* xp = xb + (p0 + i) * 10;     // wave-uniform address
        float x0 = xp[0], x1 = xp[1], x2 = xp[2];
        float rn = x0 * x0 + x1 * x1 + x2 * x2;
        float inv = 1.f / (sqrtf(rn) + 1e-8f);
        float c2[6];
        c2[0] = fmaxf(x2, 0.f) * inv; c2[1] = fmaxf(-x2, 0.f) * inv;
        c2[2] = fmaxf(x1, 0.f) * inv; c2[3] = fmaxf(-x1, 0.f) * inv;
        c2[4] = fmaxf(x0, 0.f) * inv; c2[5] = fmaxf(-x0, 0.f) * inv;
        float h = 0.f;
#pragma unroll
        for (int a = 0; a < 6; ++a) {
            float cc = c2[a] * c2[a];
            float ta = fmaf(x0, T[a * 3], fmaf(x1, T[a * 3 + 1], fmaf(x2, T[a * 3 + 2], U[a])));
            h = fmaf(cc, ta, h);
        }
        if (has0 && i == 0) h = c2v;
        accS += h;
        accQ = fmaf(h, h, accQ);
    }
    r2[t] = accS; r2[256 + t] = accQ;
    __syncthreads();
    if (t < 64) {
        ws[OFF_GP + blk * 128 + t] = r2[t] + r2[64 + t] + r2[128 + t] + r2[192 + t];
    } else if (t < 128) {
        int mm = t - 64;
        ws[OFF_GP + blk * 128 + t] = r2[256 + mm] + r2[320 + mm] + r2[384 + mm] + r2[448 + mm];
    }
}

// ---------------------------------------------------------------------------
// D: redundant GP reduction (deterministic, coalesced L2-hot) + redundant
// U2/C2 + BN3 finalize + epilogue (@Wf2 + sigmoid) -> out.
__global__ __launch_bounds__(256) void k_D(const float* __restrict__ x,
                                           const float* __restrict__ Wcm,
                                           const float* __restrict__ bcm,
                                           const float* __restrict__ g3,
                                           const float* __restrict__ b3,
                                           const float* __restrict__ Wf2,
                                           const float* __restrict__ bf2,
                                           const float* __restrict__ ws,
                                           float* __restrict__ out) {
    __shared__ float zl[128];
    __shared__ float U2l[384];
    __shared__ float C2l[64];
    __shared__ float SO[128];
    __shared__ float rr[256];
    __shared__ float T2l[1152];
    int blk = blockIdx.x, t = threadIdx.x;
    int b = blk >> 3;
    if (t < 128) zl[t] = ws[OFF_Z + b * 128 + t];
    for (int g = t; g < 1152; g += 256) T2l[g] = ws[OFF_T2 + g];
    {
        int cc = t & 127, grp = t >> 7;
        const float* gp = ws + OFF_GP + grp * 256 * 128 + cc;
        float s = 0.f;
#pragma unroll 8
        for (int r = 0; r < 256; ++r) s += gp[r * 128];
        rr[t] = s;
    }
    __syncthreads();
    {
        const float4* Vp = (const float4*)(ws + OFF_V + t * 128);
        float s = 0.f;
#pragma unroll
        for (int i = 0; i < 32; ++i) {
            float4 v = Vp[i];
            s = fmaf(zl[4 * i], v.x, s);     s = fmaf(zl[4 * i + 1], v.y, s);
            s = fmaf(zl[4 * i + 2], v.z, s); s = fmaf(zl[4 * i + 3], v.w, s);
        }
        U2l[t] = s;
    }
    if (t < 128) {
        const float4* Vp = (const float4*)(ws + OFF_V + (256 + t) * 128);
        float s = 0.f;
#pragma unroll
        for (int i = 0; i < 32; ++i) {
            float4 v = Vp[i];
            s = fmaf(zl[4 * i], v.x, s);     s = fmaf(zl[4 * i + 1], v.y, s);
            s = fmaf(zl[4 * i + 2], v.z, s); s = fmaf(zl[4 * i + 3], v.w, s);
        }
        U2l[256 + t] = s;
    }
    if (t < 64) {
        float S = rr[t] + rr[128 + t];
        float Q = rr[64 + t] + rr[192 + t];
        float mean = S * (1.f / 131072.f);
        float var = Q * (1.f / 131072.f) - mean * mean;
        float scale = g3[t] * rsqrtf(var + 1e-5f);
        SO[t] = scale; SO[64 + t] = b3[t] - mean * scale;
    }
    if ((blk & 7) == 0 && t < 64) {
        const float* w = Wcm + t * 131;
        float s = bcm[t];
#pragma unroll 8
        for (int i = 0; i < 128; ++i) s = fmaf(zl[i], w[i], s);
        const float* xp = x + (size_t)b * NPTS * 10;
        s = fmaf(xp[0], w[128], s);
        s = fmaf(xp[1], w[129], s);
        s = fmaf(xp[2], w[130], s);
        C2l[t] = s;
    }
    __syncthreads();
    // epilogue: thread = point
    int idx = blk * 256 + t;
    int n = idx & 2047;
    const float* xp = x + (size_t)idx * 10;
    float x0 = xp[0], x1 = xp[1], x2 = xp[2];
    float rn = x0 * x0 + x1 * x1 + x2 * x2;
    float inv = 1.f / (sqrtf(rn) + 1e-8f);
    float c2[6];
    c2[0] = fmaxf(x2, 0.f) * inv; c2[1] = fmaxf(-x2, 0.f) * inv;
    c2[2] = fmaxf(x1, 0.f) * inv; c2[3] = fmaxf(-x1, 0.f) * inv;
    c2[4] = fmaxf(x0, 0.f) * inv; c2[5] = fmaxf(-x0, 0.f) * inv;
#pragma unroll
    for (int a = 0; a < 6; ++a) c2[a] *= c2[a];
    bool c0 = (n == 0);
    float y[7];
#pragma unroll
    for (int k = 0; k < 7; ++k) y[k] = bf2[k];
    for (int m = 0; m < 64; ++m) {
        float h = 0.f;
#pragma unroll
        for (int a = 0; a < 6; ++a) {
            float ta = fmaf(x0, T2l[m * 18 + a * 3],
                       fmaf(x1, T2l[m * 18 + a * 3 + 1],
                       fmaf(x2, T2l[m * 18 + a * 3 + 2], U2l[m * 6 + a])));
            h = fmaf(c2[a], ta, h);
        }
        if (c0) h = C2l[m];
        float tt = fmaf(h, SO[m], SO[64 + m]);
        float r = fmaxf(tt, 0.f);
#pragma unroll
        for (int k = 0; k < 7; ++k) y[k] = fmaf(r, Wf2[k * 64 + m], y[k]);
    }
    float* op = out + (size_t)idx * 7;
#pragma unroll
    for (int k = 0; k < 7; ++k) op[k] = 1.f / (1.f + __expf(-y[k]));
}

// ---------------------------------------------------------------------------
extern "C" void kernel_launch(void* const* d_in, const int* in_sizes, int n_in,
                              void* d_out, int out_size, void* d_ws, size_t ws_size,
                              hipStream_t stream) {
    const float* x     = (const float*)d_in[0];
    // d_in[1]=Wc, d_in[2]=bc : dead code in reference (center is unused)
    const float* Wdir  = (const float*)d_in[3];
    const float* g1    = (const float*)d_in[4];
    const float* b1    = (const float*)d_in[5];
    const float* Wdir2 = (const float*)d_in[6];
    const float* g2    = (const float*)d_in[7];
    const float* b2    = (const float*)d_in[8];
    const float* Wf1   = (const float*)d_in[9];
    const float* bf1   = (const float*)d_in[10];
    const float* Wcm   = (const float*)d_in[11];
    const float* bcm   = (const float*)d_in[12];
    const float* Wdc   = (const float*)d_in[13];
    const float* Wm0   = (const float*)d_in[14];
    const float* g3    = (const float*)d_in[15];
    const float* b3    = (const float*)d_in[16];
    const float* Wf2   = (const float*)d_in[17];
    const float* bf2   = (const float*)d_in[18];
    float* ws  = (float*)d_ws;
    float* out = (float*)d_out;

    k_A<<<261, 256, 0, stream>>>(x, Wm0, Wdc, ws);
    k_B<<<16,  256, 0, stream>>>(Wdir, g1, b1, Wdir2, g2, b2, Wf1, bf1, ws);
    k_C<<<512, 256, 0, stream>>>(x, Wcm, bcm, ws);
    k_D<<<512, 256, 0, stream>>>(x, Wcm, bcm, g3, b3, Wf2, bf2, ws, out);
}

// Round 6
// 235.227 us; speedup vs baseline: 1.0179x; 1.0179x over previous
//
#include <hip/hip_runtime.h>
#include <math.h>

// Problem constants
#define NPTS  2048
// ws float offsets (total 159744 floats = 624 KB)
#define OFF_M   0        // [64][61]  M[b][c*6+a], Sdw at [b][60]
#define OFF_T2  4096     // [64][19]  T2[m][a*3+j] (stride 19, slot 18 unused)
#define OFF_V   8192     // [384][128] V[ma][v]
#define OFF_Z   57344    // [64][128]
#define OFF_U2  65536    // [64][384]
#define OFF_C2  90112    // [64][64]
#define OFF_GP  94208    // [512][128] bn3 partials (S 0..63, Q 64..127)

// ---------------------------------------------------------------------------
// A = weight fold (blocks 0..196) U per-batch moments (blocks 197..260).
__global__ __launch_bounds__(256) void k_A(const float* __restrict__ x,
                                           const float* __restrict__ Wm0,
                                           const float* __restrict__ Wdc,
                                           float* __restrict__ ws) {
    __shared__ float red[61 * 257];
    int blk = blockIdx.x, t = threadIdx.x;
    if (blk < 197) {
        int idx = blk * 256 + t;
        if (idx < 384 * 128) {
            int ma = idx >> 7, v = idx & 127;
            int a = ma % 6;
            const float* wm = Wm0 + (ma / 6) * 256;   // wave-uniform
            float s = 0.f;
#pragma unroll 8
            for (int e = 0; e < 256; ++e)
                s = fmaf(wm[e], Wdc[(e * 6 + a) * 131 + 3 + v], s);
            ws[OFF_V + ma * 128 + v] = s;
        } else if (idx < 384 * 128 + 64 * 18) {
            int j2 = idx - 384 * 128;
            int m = j2 / 18, r = j2 % 18;
            int a = r / 3, j = r % 3;
            const float* wm = Wm0 + m * 256;
            float s = 0.f;
#pragma unroll 8
            for (int e = 0; e < 256; ++e)
                s = fmaf(wm[e], Wdc[(e * 6 + a) * 131 + j], s);
            ws[OFF_T2 + m * 19 + r] = s;          // stride 19
        }
        return;
    }
    int b = blk - 197;
    float acc[61];
#pragma unroll
    for (int i = 0; i < 61; ++i) acc[i] = 0.f;
    for (int k = 0; k < 8; ++k) {
        int n = t + 256 * k;
        const float* xp = x + (size_t)(b * NPTS + n) * 10;
        float xv[10];
#pragma unroll
        for (int j = 0; j < 5; ++j) {
            float2 v = *(const float2*)(xp + 2 * j);
            xv[2 * j] = v.x; xv[2 * j + 1] = v.y;
        }
        float x0 = xv[0], x1 = xv[1], x2 = xv[2];
        float rn = x0 * x0 + x1 * x1 + x2 * x2;
        float norm = sqrtf(rn);
        float inv = 1.f / (norm + 1e-8f);
        float c2[6];
        c2[0] = fmaxf(x2, 0.f) * inv; c2[1] = fmaxf(-x2, 0.f) * inv;
        c2[2] = fmaxf(x1, 0.f) * inv; c2[3] = fmaxf(-x1, 0.f) * inv;
        c2[4] = fmaxf(x0, 0.f) * inv; c2[5] = fmaxf(-x0, 0.f) * inv;
#pragma unroll
        for (int a = 0; a < 6; ++a) c2[a] *= c2[a];
        float dw = 1.f - (rn - 1.f) * (1.f / 3.f);
        if (dw < 0.f) dw = 0.f;
        if (norm <= 0.f) dw = 0.f;
        float cw[6];
#pragma unroll
        for (int a = 0; a < 6; ++a) cw[a] = c2[a] * dw;
#pragma unroll
        for (int c = 0; c < 10; ++c) {
            float dv = (c < 7) ? xv[3 + c] : xv[c - 7];
#pragma unroll
            for (int a = 0; a < 6; ++a)
                acc[c * 6 + a] = fmaf(dv, cw[a], acc[c * 6 + a]);
        }
        acc[60] += dw;
    }
#pragma unroll
    for (int i = 0; i < 61; ++i) red[i * 257 + t] = acc[i];
    __syncthreads();
    if (t < 61) {
        float s = 0.f;
#pragma unroll 8
        for (int j = 0; j < 256; ++j) s += red[t * 257 + j];
        ws[OFF_M + b * 61 + t] = s;
    }
}

// ---------------------------------------------------------------------------
// B: h1 + BN1 + d2 + BN2 + enc + z, 16 blocks, no scattered global loads:
// every weight matrix staged coalesced into LDS, per-lane rows hoisted to
// registers, d2 accumulated in accB[64] registers.
__global__ __launch_bounds__(256) void k_B(const float* __restrict__ Wdir,
                                           const float* __restrict__ g1,
                                           const float* __restrict__ b1,
                                           const float* __restrict__ Wdir2,
                                           const float* __restrict__ g2,
                                           const float* __restrict__ b2,
                                           const float* __restrict__ Wf1,
                                           const float* __restrict__ bf1,
                                           float* __restrict__ ws) {
    __shared__ float bufA[4352];   // Wdir [64][61] -> Wdir2 chunks [16][257] -> Wf1 halves [32][129]
    __shared__ float bufB[4352];   // h1 [64][68] (float4-aligned rows)
    __shared__ float bufME[4112];  // M [64*61] -> El [16][257]
    __shared__ float sc[64], of[64];
    int t = threadIdx.x;
    int bb = blockIdx.x & 3, vb = blockIdx.x >> 2;
    // stage M + Wdir (both coalesced reads)
    for (int g = t; g < 3904; g += 256) bufME[g] = ws[OFF_M + g];
    for (int g = t; g < 3840; g += 256) bufA[(g / 60) * 61 + g % 60] = Wdir[g];
    __syncthreads();
    // phase 1: h1[b][m]; lane m, 16 b's; Wdir row from LDS (stride 61, conflict-free)
    int m = t & 63, bg = t >> 6;
    {
        float Wr[60];
#pragma unroll
        for (int r = 0; r < 60; ++r) Wr[r] = bufA[m * 61 + r];
#pragma unroll
        for (int i = 0; i < 16; ++i) {
            int b = bg * 16 + i;
            const float* Mb = bufME + b * 61;       // broadcast LDS reads
            float s = 0.f;
#pragma unroll
            for (int a = 0; a < 6; ++a)
#pragma unroll
                for (int c = 0; c < 10; ++c)
                    s = fmaf(Wr[a * 10 + c], Mb[c * 6 + a], s);
            bufB[b * 68 + m] = s / Mb[60];
        }
    }
    __syncthreads();
    // phase 2: BN1
    if (t < 64) {
        float s = 0.f, q = 0.f;
#pragma unroll 8
        for (int b = 0; b < 64; ++b) { float v = bufB[b * 68 + t]; s += v; q = fmaf(v, v, q); }
        float mean = s * (1.f / 64.f);
        float var = q * (1.f / 64.f) - mean * mean;
        float scale = g1[t] * rsqrtf(var + 1e-5f);
        sc[t] = scale; of[t] = b1[t] - mean * scale;
    }
    __syncthreads();
#pragma unroll
    for (int i = 0; i < 16; ++i) {
        int b = bg * 16 + i;
        float v = bufB[b * 68 + m];
        bufB[b * 68 + m] = fmaxf(fmaf(v, sc[m], of[m]), 0.f);
    }
    __syncthreads();
    // phase 3: d2[b][t] for all b in accB registers; Wdir2 staged in 4 r-chunks
    float accB[64];
#pragma unroll
    for (int b = 0; b < 64; ++b) accB[b] = 0.f;
    for (int rc = 0; rc < 4; ++rc) {
        // stage Wdir2[:, rc*16..+16] as Wt[rr][e]
        for (int g = t; g < 4096; g += 256)
            bufA[(g & 15) * 257 + (g >> 4)] = Wdir2[(g >> 4) * 64 + rc * 16 + (g & 15)];
        __syncthreads();
        float wt[16];
#pragma unroll
        for (int rr = 0; rr < 16; ++rr) wt[rr] = bufA[rr * 257 + t];
#pragma unroll
        for (int b = 0; b < 64; ++b) {
            const float4* h4 = (const float4*)(bufB + b * 68 + rc * 16);  // broadcast b128
            float4 h0 = h4[0], h1v = h4[1], h2 = h4[2], h3 = h4[3];
            float a0 = accB[b];
            a0 = fmaf(h0.x, wt[0], a0);  a0 = fmaf(h0.y, wt[1], a0);
            a0 = fmaf(h0.z, wt[2], a0);  a0 = fmaf(h0.w, wt[3], a0);
            a0 = fmaf(h1v.x, wt[4], a0); a0 = fmaf(h1v.y, wt[5], a0);
            a0 = fmaf(h1v.z, wt[6], a0); a0 = fmaf(h1v.w, wt[7], a0);
            a0 = fmaf(h2.x, wt[8], a0);  a0 = fmaf(h2.y, wt[9], a0);
            a0 = fmaf(h2.z, wt[10], a0); a0 = fmaf(h2.w, wt[11], a0);
            a0 = fmaf(h3.x, wt[12], a0); a0 = fmaf(h3.y, wt[13], a0);
            a0 = fmaf(h3.z, wt[14], a0); a0 = fmaf(h3.w, wt[15], a0);
            accB[b] = a0;
        }
        __syncthreads();
    }
    // BN2 stats (exact: this thread owns column e=t over all b)
    {
        float s = 0.f, q = 0.f;
#pragma unroll
        for (int b = 0; b < 64; ++b) { s += accB[b]; q = fmaf(accB[b], accB[b], q); }
        float mean = s * (1.f / 64.f);
        float var = q * (1.f / 64.f) - mean * mean;
        float scale = g2[t] * rsqrtf(var + 1e-5f);
        float off = b2[t] - mean * scale;
        // enc tile for this block's 16 b rows -> El (bufME; M is dead)
#pragma unroll
        for (int i = 0; i < 16; ++i)
            bufME[i * 257 + t] = fmaxf(fmaf(accB[bb * 16 + i], scale, off), 0.f);
    }
    __syncthreads();
    // phase 4: z tile; Wf1 halves staged into bufA
    int v_loc = t & 31, b_loc = t >> 5;
    float s0 = 0.f, s1 = 0.f;
    for (int half = 0; half < 2; ++half) {
        for (int g = t; g < 4096; g += 256)
            bufA[(g >> 7) * 129 + (g & 127)] =
                Wf1[(vb * 32 + (g >> 7)) * 256 + half * 128 + (g & 127)];
        __syncthreads();
        const float* W  = bufA + v_loc * 129;
        const float* E0 = bufME + b_loc * 257 + half * 128;
        const float* E1 = bufME + (b_loc + 8) * 257 + half * 128;
#pragma unroll 8
        for (int e = 0; e < 128; ++e) {
            float w = W[e];
            s0 = fmaf(E0[e], w, s0);
            s1 = fmaf(E1[e], w, s1);
        }
        __syncthreads();
    }
    int v = vb * 32 + v_loc;
    float bias = bf1[v];
    ws[OFF_Z + (bb * 16 + b_loc) * 128 + v] = s0 + bias;
    ws[OFF_Z + (bb * 16 + b_loc + 8) * 128 + v] = s1 + bias;
}

// ---------------------------------------------------------------------------
// U: one block per b -> U2[b][384], C2[b][64] materialized once.
__global__ __launch_bounds__(256) void k_U(const float* __restrict__ x,
                                           const float* __restrict__ Wcm,
                                           const float* __restrict__ bcm,
                                           float* __restrict__ ws) {
    __shared__ float zl[128];
    int b = blockIdx.x, t = threadIdx.x;
    if (t < 128) zl[t] = ws[OFF_Z + b * 128 + t];
    __syncthreads();
    {
        const float4* Vp = (const float4*)(ws + OFF_V + t * 128);
        float s = 0.f;
#pragma unroll
        for (int i = 0; i < 32; ++i) {
            float4 v = Vp[i];
            s = fmaf(zl[4 * i], v.x, s);     s = fmaf(zl[4 * i + 1], v.y, s);
            s = fmaf(zl[4 * i + 2], v.z, s); s = fmaf(zl[4 * i + 3], v.w, s);
        }
        ws[OFF_U2 + b * 384 + t] = s;
    }
    if (t < 128) {
        const float4* Vp = (const float4*)(ws + OFF_V + (256 + t) * 128);
        float s = 0.f;
#pragma unroll
        for (int i = 0; i < 32; ++i) {
            float4 v = Vp[i];
            s = fmaf(zl[4 * i], v.x, s);     s = fmaf(zl[4 * i + 1], v.y, s);
            s = fmaf(zl[4 * i + 2], v.z, s); s = fmaf(zl[4 * i + 3], v.w, s);
        }
        ws[OFF_U2 + b * 384 + 256 + t] = s;
    }
    if (t < 64) {
        const float* w = Wcm + t * 131;
        float s = bcm[t];
#pragma unroll 8
        for (int i = 0; i < 128; ++i) s = fmaf(zl[i], w[i], s);
        const float* xp = x + (size_t)b * NPTS * 10;
        s = fmaf(xp[0], w[128], s);
        s = fmaf(xp[1], w[129], s);
        s = fmaf(xp[2], w[130], s);
        ws[OFF_C2 + b * 64 + t] = s;
    }
}

// ---------------------------------------------------------------------------
// C: BN3 stats over this block's 256 points; U2/C2/T2 staged coalesced.
__global__ __launch_bounds__(256) void k_C(const float* __restrict__ x,
                                           float* __restrict__ ws) {
    __shared__ float U2l[384];
    __shared__ float C2l[64];
    __shared__ float T2l[1216];
    __shared__ float r2[512];
    int blk = blockIdx.x, t = threadIdx.x;
    int b = blk >> 3, c = blk & 7;
    for (int g = t; g < 1216; g += 256) T2l[g] = ws[OFF_T2 + g];
    if (t < 128) {
        U2l[t]       = ws[OFF_U2 + b * 384 + t];
        U2l[128 + t] = ws[OFF_U2 + b * 384 + 128 + t];
        U2l[256 + t] = ws[OFF_U2 + b * 384 + 256 + t];
    }
    if (c == 0 && t < 64) C2l[t] = ws[OFF_C2 + b * 64 + t];
    __syncthreads();
    int m = t & 63, wid = t >> 6;
    float T[18], U[6];
#pragma unroll
    for (int r = 0; r < 18; ++r) T[r] = T2l[m * 19 + r];
#pragma unroll
    for (int a = 0; a < 6; ++a) U[a] = U2l[m * 6 + a];
    bool has0 = (c == 0) && (wid == 0);
    float c2v = has0 ? C2l[m] : 0.f;
    float accS = 0.f, accQ = 0.f;
    int p0 = c * 256 + wid * 64;
    const float* xb = x + (size_t)b * NPTS * 10;
#pragma unroll 4
    for (int i = 0; i < 64; ++i) {
        const float* xp = xb + (p0 + i) * 10;     // wave-uniform -> s_load
        float x0 = xp[0], x1 = xp[1], x2 = xp[2];
        float rn = x0 * x0 + x1 * x1 + x2 * x2;
        float inv = 1.f / (sqrtf(rn) + 1e-8f);
        float c2[6];
        c2[0] = fmaxf(x2, 0.f) * inv; c2[1] = fmaxf(-x2, 0.f) * inv;
        c2[2] = fmaxf(x1, 0.f) * inv; c2[3] = fmaxf(-x1, 0.f) * inv;
        c2[4] = fmaxf(x0, 0.f) * inv; c2[5] = fmaxf(-x0, 0.f) * inv;
        float h = 0.f;
#pragma unroll
        for (int a = 0; a < 6; ++a) {
            float cc = c2[a] * c2[a];
            float ta = fmaf(x0, T[a * 3], fmaf(x1, T[a * 3 + 1], fmaf(x2, T[a * 3 + 2], U[a])));
            h = fmaf(cc, ta, h);
        }
        if (has0 && i == 0) h = c2v;
        accS += h;
        accQ = fmaf(h, h, accQ);
    }
    r2[t] = accS; r2[256 + t] = accQ;
    __syncthreads();
    if (t < 64) {
        ws[OFF_GP + blk * 128 + t] = r2[t] + r2[64 + t] + r2[128 + t] + r2[192 + t];
    } else if (t < 128) {
        int mm = t - 64;
        ws[OFF_GP + blk * 128 + t] = r2[256 + mm] + r2[320 + mm] + r2[384 + mm] + r2[448 + mm];
    }
}

// ---------------------------------------------------------------------------
// D: redundant GP reduce (coalesced, L2-hot) + staged U2/C2/Wf2 + epilogue.
__global__ __launch_bounds__(256) void k_D(const float* __restrict__ x,
                                           const float* __restrict__ g3,
                                           const float* __restrict__ b3,
                                           const float* __restrict__ Wf2,
                                           const float* __restrict__ bf2,
                                           const float* __restrict__ ws,
                                           float* __restrict__ out) {
    __shared__ float U2l[384];
    __shared__ float C2l[64];
    __shared__ float SO[128];
    __shared__ float rr[256];
    __shared__ float T2l[1216];
    __shared__ float Wf2l[448];
    int blk = blockIdx.x, t = threadIdx.x;
    int b = blk >> 3;
    for (int g = t; g < 1216; g += 256) T2l[g] = ws[OFF_T2 + g];
    if (t < 128) {
        U2l[t]       = ws[OFF_U2 + b * 384 + t];
        U2l[128 + t] = ws[OFF_U2 + b * 384 + 128 + t];
        U2l[256 + t] = ws[OFF_U2 + b * 384 + 256 + t];
    }
    if ((blk & 7) == 0 && t < 64) C2l[t] = ws[OFF_C2 + b * 64 + t];
    for (int g = t; g < 448; g += 256) Wf2l[g] = Wf2[g];   // R5 bug fix: full strided stage
    {
        int cc = t & 127, grp = t >> 7;
        const float* gp = ws + OFF_GP + grp * 256 * 128 + cc;
        float s = 0.f;
#pragma unroll 8
        for (int r = 0; r < 256; ++r) s += gp[r * 128];
        rr[t] = s;
    }
    __syncthreads();
    if (t < 64) {
        float S = rr[t] + rr[128 + t];
        float Q = rr[64 + t] + rr[192 + t];
        float mean = S * (1.f / 131072.f);
        float var = Q * (1.f / 131072.f) - mean * mean;
        float scale = g3[t] * rsqrtf(var + 1e-5f);
        SO[t] = scale; SO[64 + t] = b3[t] - mean * scale;
    }
    __syncthreads();
    // epilogue: thread = point
    int idx = blk * 256 + t;
    int n = idx & 2047;
    const float* xp = x + (size_t)idx * 10;
    float x0 = xp[0], x1 = xp[1], x2 = xp[2];
    float rn = x0 * x0 + x1 * x1 + x2 * x2;
    float inv = 1.f / (sqrtf(rn) + 1e-8f);
    float c2[6];
    c2[0] = fmaxf(x2, 0.f) * inv; c2[1] = fmaxf(-x2, 0.f) * inv;
    c2[2] = fmaxf(x1, 0.f) * inv; c2[3] = fmaxf(-x1, 0.f) * inv;
    c2[4] = fmaxf(x0, 0.f) * inv; c2[5] = fmaxf(-x0, 0.f) * inv;
#pragma unroll
    for (int a = 0; a < 6; ++a) c2[a] *= c2[a];
    bool c0 = (n == 0);
    float y[7];
#pragma unroll
    for (int k = 0; k < 7; ++k) y[k] = bf2[k];
    for (int m = 0; m < 64; ++m) {
        float h = 0.f;
#pragma unroll
        for (int a = 0; a < 6; ++a) {
            float ta = fmaf(x0, T2l[m * 19 + a * 3],
                       fmaf(x1, T2l[m * 19 + a * 3 + 1],
                       fmaf(x2, T2l[m * 19 + a * 3 + 2], U2l[m * 6 + a])));
            h = fmaf(c2[a], ta, h);
        }
        if (c0) h = C2l[m];
        float tt = fmaf(h, SO[m], SO[64 + m]);
        float r = fmaxf(tt, 0.f);
#pragma unroll
        for (int k = 0; k < 7; ++k) y[k] = fmaf(r, Wf2l[k * 64 + m], y[k]);
    }
    float* op = out + (size_t)idx * 7;
#pragma unroll
    for (int k = 0; k < 7; ++k) op[k] = 1.f / (1.f + __expf(-y[k]));
}

// ---------------------------------------------------------------------------
extern "C" void kernel_launch(void* const* d_in, const int* in_sizes, int n_in,
                              void* d_out, int out_size, void* d_ws, size_t ws_size,
                              hipStream_t stream) {
    const float* x     = (const float*)d_in[0];
    // d_in[1]=Wc, d_in[2]=bc : dead code in reference (center is unused)
    const float* Wdir  = (const float*)d_in[3];
    const float* g1    = (const float*)d_in[4];
    const float* b1    = (const float*)d_in[5];
    const float* Wdir2 = (const float*)d_in[6];
    const float* g2    = (const float*)d_in[7];
    const float* b2    = (const float*)d_in[8];
    const float* Wf1   = (const float*)d_in[9];
    const float* bf1   = (const float*)d_in[10];
    const float* Wcm   = (const float*)d_in[11];
    const float* bcm   = (const float*)d_in[12];
    const float* Wdc   = (const float*)d_in[13];
    const float* Wm0   = (const float*)d_in[14];
    const float* g3    = (const float*)d_in[15];
    const float* b3    = (const float*)d_in[16];
    const float* Wf2   = (const float*)d_in[17];
    const float* bf2   = (const float*)d_in[18];
    float* ws  = (float*)d_ws;
    float* out = (float*)d_out;

    k_A<<<261, 256, 0, stream>>>(x, Wm0, Wdc, ws);
    k_B<<<16,  256, 0, stream>>>(Wdir, g1, b1, Wdir2, g2, b2, Wf1, bf1, ws);
    k_U<<<64,  256, 0, stream>>>(x, Wcm, bcm, ws);
    k_C<<<512, 256, 0, stream>>>(x, ws);
    k_D<<<512, 256, 0, stream>>>(x, g3, b3, Wf2, bf2, ws, out);
}

// Round 7
// 214.718 us; speedup vs baseline: 1.1151x; 1.0955x over previous
//
#include <hip/hip_runtime.h>
#include <math.h>

// Problem constants
#define NPTS  2048
// ws float offsets (total 163584 floats = 654 KB)
#define OFF_M   0        // [61][64]  Mt[k][b], k=a*10+c (0..59), Sdw row at k=60
#define OFF_T2  4096     // [64][19]  T2[m][a*3+j] (stride 19)
#define OFF_V   8192     // [384][128] V[ma][v]
#define OFF_Z   57344    // [64][128]
#define OFF_U2  65536    // [64][384]
#define OFF_C2  90112    // [64][64]
#define OFF_GP  94208    // [512][128] bn3 partials (S 0..63, Q 64..127)
#define OFF_WT  159744   // [60][64]  WdirT[k][m]

// ---------------------------------------------------------------------------
// A = weight fold (0..196) U per-batch moments (197..260) U WdirT (261..275).
__global__ __launch_bounds__(256) void k_A(const float* __restrict__ x,
                                           const float* __restrict__ Wm0,
                                           const float* __restrict__ Wdc,
                                           const float* __restrict__ Wdir,
                                           float* __restrict__ ws) {
    __shared__ float red[61 * 257];
    int blk = blockIdx.x, t = threadIdx.x;
    if (blk < 197) {
        int idx = blk * 256 + t;
        if (idx < 384 * 128) {
            int ma = idx >> 7, v = idx & 127;
            int a = ma % 6;
            const float* wm = Wm0 + (ma / 6) * 256;   // wave-uniform
            float s = 0.f;
#pragma unroll 8
            for (int e = 0; e < 256; ++e)
                s = fmaf(wm[e], Wdc[(e * 6 + a) * 131 + 3 + v], s);
            ws[OFF_V + ma * 128 + v] = s;
        } else if (idx < 384 * 128 + 64 * 18) {
            int j2 = idx - 384 * 128;
            int m = j2 / 18, r = j2 % 18;
            int a = r / 3, j = r % 3;
            const float* wm = Wm0 + m * 256;
            float s = 0.f;
#pragma unroll 8
            for (int e = 0; e < 256; ++e)
                s = fmaf(wm[e], Wdc[(e * 6 + a) * 131 + j], s);
            ws[OFF_T2 + m * 19 + r] = s;
        }
        return;
    }
    if (blk >= 261) {
        // WdirT[r][m] = Wdir[m*60+r]
        int idx2 = (blk - 261) * 256 + t;   // 0..3839
        int r = idx2 >> 6, m = idx2 & 63;
        ws[OFF_WT + r * 64 + m] = Wdir[m * 60 + r];
        return;
    }
    // ---- per-batch moments: Mt[k][b], k = a*10+c ----
    int b = blk - 197;
    float acc[61];
#pragma unroll
    for (int i = 0; i < 61; ++i) acc[i] = 0.f;
    for (int k = 0; k < 8; ++k) {
        int n = t + 256 * k;
        const float* xp = x + (size_t)(b * NPTS + n) * 10;
        float xv[10];
#pragma unroll
        for (int j = 0; j < 5; ++j) {
            float2 v = *(const float2*)(xp + 2 * j);
            xv[2 * j] = v.x; xv[2 * j + 1] = v.y;
        }
        float x0 = xv[0], x1 = xv[1], x2 = xv[2];
        float rn = x0 * x0 + x1 * x1 + x2 * x2;
        float norm = sqrtf(rn);
        float inv = 1.f / (norm + 1e-8f);
        float c2[6];
        c2[0] = fmaxf(x2, 0.f) * inv; c2[1] = fmaxf(-x2, 0.f) * inv;
        c2[2] = fmaxf(x1, 0.f) * inv; c2[3] = fmaxf(-x1, 0.f) * inv;
        c2[4] = fmaxf(x0, 0.f) * inv; c2[5] = fmaxf(-x0, 0.f) * inv;
#pragma unroll
        for (int a = 0; a < 6; ++a) c2[a] *= c2[a];
        float dw = 1.f - (rn - 1.f) * (1.f / 3.f);
        if (dw < 0.f) dw = 0.f;
        if (norm <= 0.f) dw = 0.f;
        float cw[6];
#pragma unroll
        for (int a = 0; a < 6; ++a) cw[a] = c2[a] * dw;
#pragma unroll
        for (int c = 0; c < 10; ++c) {
            float dv = (c < 7) ? xv[3 + c] : xv[c - 7];
#pragma unroll
            for (int a = 0; a < 6; ++a)
                acc[a * 10 + c] = fmaf(dv, cw[a], acc[a * 10 + c]);
        }
        acc[60] += dw;
    }
#pragma unroll
    for (int i = 0; i < 61; ++i) red[i * 257 + t] = acc[i];
    __syncthreads();
    if (t < 61) {
        float s = 0.f;
#pragma unroll 8
        for (int j = 0; j < 256; ++j) s += red[t * 257 + j];
        ws[OFF_M + t * 64 + b] = s;   // transposed: Mt[k][b]
    }
}

// ---------------------------------------------------------------------------
// B: register-tiled h1 -> BN1 -> d2 -> BN2 -> enc -> z. 16 blocks, redundant
// deterministic stats, disjoint z-tile writes. LDS instrs per FMA minimized:
// phase1 2xb128/16FMA, phase3 3xb128/32FMA, z 3xb128/8FMA.
__global__ __launch_bounds__(256) void k_B(const float* __restrict__ g1,
                                           const float* __restrict__ b1,
                                           const float* __restrict__ Wdir2,
                                           const float* __restrict__ g2,
                                           const float* __restrict__ b2,
                                           const float* __restrict__ Wf1,
                                           const float* __restrict__ bf1,
                                           float* __restrict__ ws) {
    // regA: MtL[61][68](4148)+WtL[60][68](4080) -> Wt2L[64][132](8448)
    //       -> rS[256][17]+rQ[256][17](8704) -> Wf1L[32][260](8320)
    __shared__ float regA[8704];
    // regB: h1T[64][68](4352) -> enc2[16][260](4160)
    __shared__ float regB[4352];
    __shared__ float sc1[64], of1[64], sc2[256], of2[256];
    int t = threadIdx.x;
    int bb = blockIdx.x & 3, vb = blockIdx.x >> 2;

    // stage MtL + WtL (coalesced global, conflict-free LDS writes)
    for (int g = t; g < 3904; g += 256) regA[(g >> 6) * 68 + (g & 63)] = ws[OFF_M + g];
    for (int g = t; g < 3840; g += 256) regA[4148 + (g >> 6) * 68 + (g & 63)] = ws[OFF_WT + g];
    __syncthreads();

    // ---- phase 1: h1 tile 4b x 4m per thread ----
    int tb1 = t & 15, tm1 = t >> 4;       // b0 = tb1*4, m0 = tm1*4
    float h[16];
#pragma unroll
    for (int i = 0; i < 16; ++i) h[i] = 0.f;
#pragma unroll 4
    for (int k = 0; k < 60; ++k) {
        float4 mb = *(const float4*)(regA + k * 68 + tb1 * 4);
        float4 wd = *(const float4*)(regA + 4148 + k * 68 + tm1 * 4);
        h[0] = fmaf(mb.x, wd.x, h[0]);  h[1] = fmaf(mb.y, wd.x, h[1]);
        h[2] = fmaf(mb.z, wd.x, h[2]);  h[3] = fmaf(mb.w, wd.x, h[3]);
        h[4] = fmaf(mb.x, wd.y, h[4]);  h[5] = fmaf(mb.y, wd.y, h[5]);
        h[6] = fmaf(mb.z, wd.y, h[6]);  h[7] = fmaf(mb.w, wd.y, h[7]);
        h[8] = fmaf(mb.x, wd.z, h[8]);  h[9] = fmaf(mb.y, wd.z, h[9]);
        h[10] = fmaf(mb.z, wd.z, h[10]); h[11] = fmaf(mb.w, wd.z, h[11]);
        h[12] = fmaf(mb.x, wd.w, h[12]); h[13] = fmaf(mb.y, wd.w, h[13]);
        h[14] = fmaf(mb.z, wd.w, h[14]); h[15] = fmaf(mb.w, wd.w, h[15]);
    }
    {
        float4 sd = *(const float4*)(regA + 60 * 68 + tb1 * 4);
#pragma unroll
        for (int j = 0; j < 4; ++j) {
            h[j * 4 + 0] /= sd.x; h[j * 4 + 1] /= sd.y;
            h[j * 4 + 2] /= sd.z; h[j * 4 + 3] /= sd.w;
        }
    }
    // raw h1 -> h1T[m][b]
#pragma unroll
    for (int j = 0; j < 4; ++j)
#pragma unroll
        for (int i = 0; i < 4; ++i)
            regB[(tm1 * 4 + j) * 68 + tb1 * 4 + i] = h[j * 4 + i];
    __syncthreads();
    // BN1 stats
    if (t < 64) {
        float s = 0.f, q = 0.f;
#pragma unroll
        for (int j = 0; j < 16; ++j) {
            float4 v = *(const float4*)(regB + t * 68 + j * 4);
            s += v.x + v.y + v.z + v.w;
            q = fmaf(v.x, v.x, q); q = fmaf(v.y, v.y, q);
            q = fmaf(v.z, v.z, q); q = fmaf(v.w, v.w, q);
        }
        float mean = s * (1.f / 64.f);
        float var = q * (1.f / 64.f) - mean * mean;
        float scale = g1[t] * rsqrtf(var + 1e-5f);
        sc1[t] = scale; of1[t] = b1[t] - mean * scale;
    }
    __syncthreads();
    // apply BN1+relu in regs, rewrite h1T
#pragma unroll
    for (int j = 0; j < 4; ++j) {
        float scl = sc1[tm1 * 4 + j], ofl = of1[tm1 * 4 + j];
#pragma unroll
        for (int i = 0; i < 4; ++i) {
            float v = fmaxf(fmaf(h[j * 4 + i], scl, ofl), 0.f);
            regB[(tm1 * 4 + j) * 68 + tb1 * 4 + i] = v;
        }
    }
    __syncthreads();

    // ---- phase 3: d2 tile 4b x 8e x 2 halves ----
    int tb3 = t >> 4, te3 = t & 15;       // b0 = tb3*4, e0 = te3*8 (per half)
    float acc[64];
#pragma unroll
    for (int i = 0; i < 64; ++i) acc[i] = 0.f;
    for (int half = 0; half < 2; ++half) {
        __syncthreads();
        // stage Wt2L[m][e] = Wdir2[e][m], e in this half (pad 132)
        for (int g = t; g < 8192; g += 256)
            regA[(g & 63) * 132 + (g >> 6)] = Wdir2[(((half << 7) + (g >> 6))) * 64 + (g & 63)];
        __syncthreads();
        float* a0 = acc + half * 32;
#pragma unroll 4
        for (int m = 0; m < 64; ++m) {
            float4 hb = *(const float4*)(regB + m * 68 + tb3 * 4);
            float4 w0 = *(const float4*)(regA + m * 132 + te3 * 8);
            float4 w1 = *(const float4*)(regA + m * 132 + te3 * 8 + 4);
            a0[0]  = fmaf(hb.x, w0.x, a0[0]);  a0[1]  = fmaf(hb.y, w0.x, a0[1]);
            a0[2]  = fmaf(hb.z, w0.x, a0[2]);  a0[3]  = fmaf(hb.w, w0.x, a0[3]);
            a0[4]  = fmaf(hb.x, w0.y, a0[4]);  a0[5]  = fmaf(hb.y, w0.y, a0[5]);
            a0[6]  = fmaf(hb.z, w0.y, a0[6]);  a0[7]  = fmaf(hb.w, w0.y, a0[7]);
            a0[8]  = fmaf(hb.x, w0.z, a0[8]);  a0[9]  = fmaf(hb.y, w0.z, a0[9]);
            a0[10] = fmaf(hb.z, w0.z, a0[10]); a0[11] = fmaf(hb.w, w0.z, a0[11]);
            a0[12] = fmaf(hb.x, w0.w, a0[12]); a0[13] = fmaf(hb.y, w0.w, a0[13]);
            a0[14] = fmaf(hb.z, w0.w, a0[14]); a0[15] = fmaf(hb.w, w0.w, a0[15]);
            a0[16] = fmaf(hb.x, w1.x, a0[16]); a0[17] = fmaf(hb.y, w1.x, a0[17]);
            a0[18] = fmaf(hb.z, w1.x, a0[18]); a0[19] = fmaf(hb.w, w1.x, a0[19]);
            a0[20] = fmaf(hb.x, w1.y, a0[20]); a0[21] = fmaf(hb.y, w1.y, a0[21]);
            a0[22] = fmaf(hb.z, w1.y, a0[22]); a0[23] = fmaf(hb.w, w1.y, a0[23]);
            a0[24] = fmaf(hb.x, w1.z, a0[24]); a0[25] = fmaf(hb.y, w1.z, a0[25]);
            a0[26] = fmaf(hb.z, w1.z, a0[26]); a0[27] = fmaf(hb.w, w1.z, a0[27]);
            a0[28] = fmaf(hb.x, w1.w, a0[28]); a0[29] = fmaf(hb.y, w1.w, a0[29]);
            a0[30] = fmaf(hb.z, w1.w, a0[30]); a0[31] = fmaf(hb.w, w1.w, a0[31]);
        }
    }
    __syncthreads();
    // column partials -> rS[256][17], rQ at 4352 (in regA; Wt2L dead)
#pragma unroll
    for (int half = 0; half < 2; ++half)
#pragma unroll
        for (int j = 0; j < 8; ++j) {
            int e = half * 128 + te3 * 8 + j;
            const float* a0 = acc + half * 32 + j * 4;
            float s = a0[0] + a0[1] + a0[2] + a0[3];
            float q = a0[0] * a0[0] + a0[1] * a0[1] + a0[2] * a0[2] + a0[3] * a0[3];
            regA[e * 17 + tb3] = s;
            regA[4352 + e * 17 + tb3] = q;
        }
    __syncthreads();
    // BN2 stats: thread e=t
    {
        float s = 0.f, q = 0.f;
#pragma unroll
        for (int i = 0; i < 16; ++i) { s += regA[t * 17 + i]; q += regA[4352 + t * 17 + i]; }
        float mean = s * (1.f / 64.f);
        float var = q * (1.f / 64.f) - mean * mean;
        float scale = g2[t] * rsqrtf(var + 1e-5f);
        sc2[t] = scale; of2[t] = b2[t] - mean * scale;
    }
    __syncthreads();
    // enc2[b_loc][e] (regB; h1T dead) for this block's 16-b window
    if ((tb3 >> 2) == bb) {
        int bl = (tb3 & 3) * 4;
#pragma unroll
        for (int half = 0; half < 2; ++half)
#pragma unroll
            for (int j = 0; j < 8; ++j) {
                int e = half * 128 + te3 * 8 + j;
                float scl = sc2[e], ofl = of2[e];
                const float* a0 = acc + half * 32 + j * 4;
#pragma unroll
                for (int i = 0; i < 4; ++i)
                    regB[(bl + i) * 260 + e] = fmaxf(fmaf(a0[i], scl, ofl), 0.f);
            }
    }
    // stage Wf1L[32][260] in regA (rS dead after stats)
    for (int g = t; g < 8192; g += 256)
        regA[(g >> 8) * 260 + (g & 255)] = Wf1[(vb * 32 + (g >> 8)) * 256 + (g & 255)];
    __syncthreads();
    // ---- phase z: thread (v_loc = t&31, 2 b's) ----
    {
        int v_loc = t & 31, tbz = t >> 5;
        float s0 = 0.f, s1 = 0.f;
        const float* W  = regA + v_loc * 260;
        const float* E0 = regB + (tbz * 2) * 260;
        const float* E1 = regB + (tbz * 2 + 1) * 260;
#pragma unroll 4
        for (int e4 = 0; e4 < 64; ++e4) {
            float4 w  = *(const float4*)(W + e4 * 4);
            float4 ea = *(const float4*)(E0 + e4 * 4);
            float4 eb = *(const float4*)(E1 + e4 * 4);
            s0 = fmaf(ea.x, w.x, s0); s0 = fmaf(ea.y, w.y, s0);
            s0 = fmaf(ea.z, w.z, s0); s0 = fmaf(ea.w, w.w, s0);
            s1 = fmaf(eb.x, w.x, s1); s1 = fmaf(eb.y, w.y, s1);
            s1 = fmaf(eb.z, w.z, s1); s1 = fmaf(eb.w, w.w, s1);
        }
        int v = vb * 32 + v_loc;
        float bias = bf1[v];
        ws[OFF_Z + (bb * 16 + tbz * 2) * 128 + v] = s0 + bias;
        ws[OFF_Z + (bb * 16 + tbz * 2 + 1) * 128 + v] = s1 + bias;
    }
}

// ---------------------------------------------------------------------------
// U: one block per b -> U2[b][384], C2[b][64] materialized once.
__global__ __launch_bounds__(256) void k_U(const float* __restrict__ x,
                                           const float* __restrict__ Wcm,
                                           const float* __restrict__ bcm,
                                           float* __restrict__ ws) {
    __shared__ float zl[128];
    int b = blockIdx.x, t = threadIdx.x;
    if (t < 128) zl[t] = ws[OFF_Z + b * 128 + t];
    __syncthreads();
    {
        const float4* Vp = (const float4*)(ws + OFF_V + t * 128);
        float s = 0.f;
#pragma unroll
        for (int i = 0; i < 32; ++i) {
            float4 v = Vp[i];
            s = fmaf(zl[4 * i], v.x, s);     s = fmaf(zl[4 * i + 1], v.y, s);
            s = fmaf(zl[4 * i + 2], v.z, s); s = fmaf(zl[4 * i + 3], v.w, s);
        }
        ws[OFF_U2 + b * 384 + t] = s;
    }
    if (t < 128) {
        const float4* Vp = (const float4*)(ws + OFF_V + (256 + t) * 128);
        float s = 0.f;
#pragma unroll
        for (int i = 0; i < 32; ++i) {
            float4 v = Vp[i];
            s = fmaf(zl[4 * i], v.x, s);     s = fmaf(zl[4 * i + 1], v.y, s);
            s = fmaf(zl[4 * i + 2], v.z, s); s = fmaf(zl[4 * i + 3], v.w, s);
        }
        ws[OFF_U2 + b * 384 + 256 + t] = s;
    }
    if (t < 64) {
        const float* w = Wcm + t * 131;
        float s = bcm[t];
#pragma unroll 8
        for (int i = 0; i < 128; ++i) s = fmaf(zl[i], w[i], s);
        const float* xp = x + (size_t)b * NPTS * 10;
        s = fmaf(xp[0], w[128], s);
        s = fmaf(xp[1], w[129], s);
        s = fmaf(xp[2], w[130], s);
        ws[OFF_C2 + b * 64 + t] = s;
    }
}

// ---------------------------------------------------------------------------
// C: BN3 stats over this block's 256 points; U2/C2/T2 staged coalesced.
__global__ __launch_bounds__(256) void k_C(const float* __restrict__ x,
                                           float* __restrict__ ws) {
    __shared__ float U2l[384];
    __shared__ float C2l[64];
    __shared__ float T2l[1216];
    __shared__ float r2[512];
    int blk = blockIdx.x, t = threadIdx.x;
    int b = blk >> 3, c = blk & 7;
    for (int g = t; g < 1216; g += 256) T2l[g] = ws[OFF_T2 + g];
    if (t < 128) {
        U2l[t]       = ws[OFF_U2 + b * 384 + t];
        U2l[128 + t] = ws[OFF_U2 + b * 384 + 128 + t];
        U2l[256 + t] = ws[OFF_U2 + b * 384 + 256 + t];
    }
    if (c == 0 && t < 64) C2l[t] = ws[OFF_C2 + b * 64 + t];
    __syncthreads();
    int m = t & 63, wid = t >> 6;
    float T[18], U[6];
#pragma unroll
    for (int r = 0; r < 18; ++r) T[r] = T2l[m * 19 + r];
#pragma unroll
    for (int a = 0; a < 6; ++a) U[a] = U2l[m * 6 + a];
    bool has0 = (c == 0) && (wid == 0);
    float c2v = has0 ? C2l[m] : 0.f;
    float accS = 0.f, accQ = 0.f;
    int p0 = c * 256 + wid * 64;
    const float* xb = x + (size_t)b * NPTS * 10;
#pragma unroll 4
    for (int i = 0; i < 64; ++i) {
        const float* xp = xb + (p0 + i) * 10;     // wave-uniform -> s_load
        float x0 = xp[0], x1 = xp[1], x2 = xp[2];
        float rn = x0 * x0 + x1 * x1 + x2 * x2;
        float inv = 1.f / (sqrtf(rn) + 1e-8f);
        float c2[6];
        c2[0] = fmaxf(x2, 0.f) * inv; c2[1] = fmaxf(-x2, 0.f) * inv;
        c2[2] = fmaxf(x1, 0.f) * inv; c2[3] = fmaxf(-x1, 0.f) * inv;
        c2[4] = fmaxf(x0, 0.f) * inv; c2[5] = fmaxf(-x0, 0.f) * inv;
        float h = 0.f;
#pragma unroll
        for (int a = 0; a < 6; ++a) {
            float cc = c2[a] * c2[a];
            float ta = fmaf(x0, T[a * 3], fmaf(x1, T[a * 3 + 1], fmaf(x2, T[a * 3 + 2], U[a])));
            h = fmaf(cc, ta, h);
        }
        if (has0 && i == 0) h = c2v;
        accS += h;
        accQ = fmaf(h, h, accQ);
    }
    r2[t] = accS; r2[256 + t] = accQ;
    __syncthreads();
    if (t < 64) {
        ws[OFF_GP + blk * 128 + t] = r2[t] + r2[64 + t] + r2[128 + t] + r2[192 + t];
    } else if (t < 128) {
        int mm = t - 64;
        ws[OFF_GP + blk * 128 + t] = r2[256 + mm] + r2[320 + mm] + r2[384 + mm] + r2[448 + mm];
    }
}

// ---------------------------------------------------------------------------
// D: redundant GP reduce (coalesced, L2-hot) + staged U2/C2/Wf2 + epilogue.
__global__ __launch_bounds__(256) void k_D(const float* __restrict__ x,
                                           const float* __restrict__ g3,
                                           const float* __restrict__ b3,
                                           const float* __restrict__ Wf2,
                                           const float* __restrict__ bf2,
                                           const float* __restrict__ ws,
                                           float* __restrict__ out) {
    __shared__ float U2l[384];
    __shared__ float C2l[64];
    __shared__ float SO[128];
    __shared__ float rr[256];
    __shared__ float T2l[1216];
    __shared__ float Wf2l[448];
    int blk = blockIdx.x, t = threadIdx.x;
    int b = blk >> 3;
    for (int g = t; g < 1216; g += 256) T2l[g] = ws[OFF_T2 + g];
    if (t < 128) {
        U2l[t]       = ws[OFF_U2 + b * 384 + t];
        U2l[128 + t] = ws[OFF_U2 + b * 384 + 128 + t];
        U2l[256 + t] = ws[OFF_U2 + b * 384 + 256 + t];
    }
    if ((blk & 7) == 0 && t < 64) C2l[t] = ws[OFF_C2 + b * 64 + t];
    for (int g = t; g < 448; g += 256) Wf2l[g] = Wf2[g];
    {
        int cc = t & 127, grp = t >> 7;
        const float* gp = ws + OFF_GP + grp * 256 * 128 + cc;
        float s = 0.f;
#pragma unroll 8
        for (int r = 0; r < 256; ++r) s += gp[r * 128];
        rr[t] = s;
    }
    __syncthreads();
    if (t < 64) {
        float S = rr[t] + rr[128 + t];
        float Q = rr[64 + t] + rr[192 + t];
        float mean = S * (1.f / 131072.f);
        float var = Q * (1.f / 131072.f) - mean * mean;
        float scale = g3[t] * rsqrtf(var + 1e-5f);
        SO[t] = scale; SO[64 + t] = b3[t] - mean * scale;
    }
    __syncthreads();
    // epilogue: thread = point
    int idx = blk * 256 + t;
    int n = idx & 2047;
    const float* xp = x + (size_t)idx * 10;
    float x0 = xp[0], x1 = xp[1], x2 = xp[2];
    float rn = x0 * x0 + x1 * x1 + x2 * x2;
    float inv = 1.f / (sqrtf(rn) + 1e-8f);
    float c2[6];
    c2[0] = fmaxf(x2, 0.f) * inv; c2[1] = fmaxf(-x2, 0.f) * inv;
    c2[2] = fmaxf(x1, 0.f) * inv; c2[3] = fmaxf(-x1, 0.f) * inv;
    c2[4] = fmaxf(x0, 0.f) * inv; c2[5] = fmaxf(-x0, 0.f) * inv;
#pragma unroll
    for (int a = 0; a < 6; ++a) c2[a] *= c2[a];
    bool c0 = (n == 0);
    float y[7];
#pragma unroll
    for (int k = 0; k < 7; ++k) y[k] = bf2[k];
    for (int m = 0; m < 64; ++m) {
        float h = 0.f;
#pragma unroll
        for (int a = 0; a < 6; ++a) {
            float ta = fmaf(x0, T2l[m * 19 + a * 3],
                       fmaf(x1, T2l[m * 19 + a * 3 + 1],
                       fmaf(x2, T2l[m * 19 + a * 3 + 2], U2l[m * 6 + a])));
            h = fmaf(c2[a], ta, h);
        }
        if (c0) h = C2l[m];
        float tt = fmaf(h, SO[m], SO[64 + m]);
        float r = fmaxf(tt, 0.f);
#pragma unroll
        for (int k = 0; k < 7; ++k) y[k] = fmaf(r, Wf2l[k * 64 + m], y[k]);
    }
    float* op = out + (size_t)idx * 7;
#pragma unroll
    for (int k = 0; k < 7; ++k) op[k] = 1.f / (1.f + __expf(-y[k]));
}

// ---------------------------------------------------------------------------
extern "C" void kernel_launch(void* const* d_in, const int* in_sizes, int n_in,
                              void* d_out, int out_size, void* d_ws, size_t ws_size,
                              hipStream_t stream) {
    const float* x     = (const float*)d_in[0];
    // d_in[1]=Wc, d_in[2]=bc : dead code in reference (center is unused)
    const float* Wdir  = (const float*)d_in[3];
    const float* g1    = (const float*)d_in[4];
    const float* b1    = (const float*)d_in[5];
    const float* Wdir2 = (const float*)d_in[6];
    const float* g2    = (const float*)d_in[7];
    const float* b2    = (const float*)d_in[8];
    const float* Wf1   = (const float*)d_in[9];
    const float* bf1   = (const float*)d_in[10];
    const float* Wcm   = (const float*)d_in[11];
    const float* bcm   = (const float*)d_in[12];
    const float* Wdc   = (const float*)d_in[13];
    const float* Wm0   = (const float*)d_in[14];
    const float* g3    = (const float*)d_in[15];
    const float* b3    = (const float*)d_in[16];
    const float* Wf2   = (const float*)d_in[17];
    const float* bf2   = (const float*)d_in[18];
    float* ws  = (float*)d_ws;
    float* out = (float*)d_out;

    k_A<<<276, 256, 0, stream>>>(x, Wm0, Wdc, Wdir, ws);
    k_B<<<16,  256, 0, stream>>>(g1, b1, Wdir2, g2, b2, Wf1, bf1, ws);
    k_U<<<64,  256, 0, stream>>>(x, Wcm, bcm, ws);
    k_C<<<512, 256, 0, stream>>>(x, ws);
    k_D<<<512, 256, 0, stream>>>(x, g3, b3, Wf2, bf2, ws, out);
}